// Round 10
// baseline (347.179 us; speedup 1.0000x reference)
//
#include <hip/hip_runtime.h>
#include <hip/hip_bf16.h>

#define SEQ   2048
#define BATCH 2
#define DMODEL 1024
#define DFF   4096
#define NHEAD 16
#define HDIM  64
#define NTOK  (BATCH*SEQ)   // 4096

typedef short s8v __attribute__((ext_vector_type(8)));
typedef float f4v __attribute__((ext_vector_type(4)));

__device__ __forceinline__ float b2f(unsigned short u) {
    union { unsigned int i; float f; } v; v.i = ((unsigned int)u) << 16; return v.f;
}
__device__ __forceinline__ unsigned short f2b(float f) {
    union { unsigned int i; float f; } v; v.f = f;
    unsigned int r = v.i + 0x7FFFu + ((v.i >> 16) & 1u);
    return (unsigned short)(r >> 16);
}
__device__ __forceinline__ ushort2 cvt_pk(float a, float b) {
    __hip_bfloat162 h = __float22bfloat162_rn(float2{ a, b });   // RNE, same as f2b
    return *(ushort2*)&h;
}

__device__ __forceinline__ f4v mfma_bf16(s8v a, s8v b, f4v c) {
    return __builtin_amdgcn_mfma_f32_16x16x32_bf16(a, b, c, 0, 0, 0);
}

__device__ __forceinline__ void gload_lds16(const void* g, void* l) {
    __builtin_amdgcn_global_load_lds(
        (const __attribute__((address_space(1))) unsigned int*)g,
        (__attribute__((address_space(3))) unsigned int*)l, 16, 0, 0);
}

template<int N> __device__ __forceinline__ void wait_vmcnt() {
    if constexpr (N == 8)      asm volatile("s_waitcnt vmcnt(8)" ::: "memory");
    else if constexpr (N == 6) asm volatile("s_waitcnt vmcnt(6)" ::: "memory");
    else if constexpr (N == 4) asm volatile("s_waitcnt vmcnt(4)" ::: "memory");
    else if constexpr (N == 2) asm volatile("s_waitcnt vmcnt(2)" ::: "memory");
    else                       asm volatile("s_waitcnt vmcnt(0)" ::: "memory");
}

// ---------------- one tile of fp32->bf16 transpose (vectorized) ----------------
__device__ __forceinline__ void tp_tile(const float* __restrict__ src,
                                        unsigned short* __restrict__ dst,
                                        int R, int C, int br, int bc, int t,
                                        unsigned short* tl) {
    for (int i = 0; i < 4; i++) {
        int lin = i * 1024 + t * 4;
        int r = lin >> 6, c = lin & 63;
        float4 u = *(const float4*)&src[(size_t)(br * 64 + r) * C + bc * 64 + c];
        tl[r * 65 + c + 0] = f2b(u.x);
        tl[r * 65 + c + 1] = f2b(u.y);
        tl[r * 65 + c + 2] = f2b(u.z);
        tl[r * 65 + c + 3] = f2b(u.w);
    }
    __syncthreads();
    for (int i = 0; i < 4; i++) {
        int lin = i * 1024 + t * 4;
        int r2 = lin >> 6, c2 = lin & 63;
        ushort4 o;
        o.x = tl[(c2 + 0) * 65 + r2];
        o.y = tl[(c2 + 1) * 65 + r2];
        o.z = tl[(c2 + 2) * 65 + r2];
        o.w = tl[(c2 + 3) * 65 + r2];
        *(ushort4*)&dst[(size_t)(bc * 64 + r2) * R + br * 64 + c2] = o;
    }
}

// ------- fused prep: weight transposes + bias concat + LN1 + mask compaction scan -------
__global__ __launch_bounds__(256) void prep_weights(const float* __restrict__ Wq,
                                                    const float* __restrict__ Wk,
                                                    const float* __restrict__ Wv,
                                                    const float* __restrict__ Wo,
                                                    const float* __restrict__ W1,
                                                    const float* __restrict__ W2,
                                                    const float* __restrict__ bq,
                                                    const float* __restrict__ bk,
                                                    const float* __restrict__ bv,
                                                    const float* __restrict__ x,
                                                    const float* __restrict__ a1,
                                                    const float* __restrict__ be1,
                                                    const int* __restrict__ msk,
                                                    unsigned short* __restrict__ Wqkv_t,
                                                    unsigned short* __restrict__ Wo_t,
                                                    unsigned short* __restrict__ W1_t,
                                                    unsigned short* __restrict__ W2_t,
                                                    float* __restrict__ bqkv,
                                                    unsigned short* __restrict__ n1,
                                                    int* __restrict__ idxc,
                                                    float* __restrict__ maskc2,
                                                    int* __restrict__ ntl) {
    __shared__ unsigned short tl[64 * 65];
    __shared__ float red[8];
    __shared__ int wsum[4];
    const int t = threadIdx.x;
    const int bx = blockIdx.x, by = blockIdx.y, z = blockIdx.z;
    if (z < 4) {
        const float* src = (z == 0) ? Wq : (z == 1) ? Wk : (z == 2) ? Wv : Wo;
        unsigned short* dst = (z == 3) ? Wo_t : Wqkv_t + (size_t)z * 1024 * 1024;
        tp_tile(src, dst, 1024, 1024, bx, by, t, tl);
    } else if (z == 4) {
        for (int i = 0; i < 4; i++) {
            tp_tile(W1, W1_t, 1024, 4096, bx, by + 16 * i, t, tl);
            __syncthreads();
        }
    } else if (z == 5) {
        if (bx == 0 && by == 0) {
            for (int i = 0; i < 12; i++) {
                int idx = t + 256 * i;
                if (idx < 1024) bqkv[idx] = bq[idx];
                else if (idx < 2048) bqkv[idx] = bk[idx - 1024];
                else if (idx < 3072) bqkv[idx] = bv[idx - 2048];
            }
        }
        for (int i = 0; i < 4; i++) {
            tp_tile(W2, W2_t, 4096, 1024, bx + 16 * i, by, t, tl);
            __syncthreads();
        }
    } else if (z == 22) {
        // mask compaction scan: one block per batch (prob of masked key == 0 exactly)
        if (bx >= BATCH || by != 0) return;
        const int b = bx;
        const int base = b * SEQ;
        int k[8]; int cnt = 0;
        for (int j = 0; j < 8; j++) {
            k[j] = (msk[base + t * 8 + j] != 0) ? 1 : 0;
            cnt += k[j];
        }
        const int lane = t & 63, wv = t >> 6;
        int pre = cnt;
        for (int off = 1; off < 64; off <<= 1) {
            int n = __shfl_up(pre, off);
            if (lane >= off) pre += n;
        }
        if (lane == 63) wsum[wv] = pre;
        __syncthreads();
        const int Nb = wsum[0] + wsum[1] + wsum[2] + wsum[3];
        int woff = 0;
        for (int w = 0; w < wv; w++) woff += wsum[w];
        const int excl = woff + pre - cnt;
        for (int j = 0; j < 8; j++) {
            int g = t * 8 + j;
            idxc[base + g] = 0;
            maskc2[base + g] = (g < Nb) ? 0.f : -1e9f;
        }
        __syncthreads();
        int pos = excl;
        for (int j = 0; j < 8; j++) {
            if (k[j]) { idxc[base + pos] = t * 8 + j; pos++; }
        }
        if (t == 0) ntl[b] = (Nb + 63) >> 6;
    } else {
        // LN1: one row per block (z in [6,22))
        const int row = (z - 6) * 256 + by * 16 + bx;
        const float* xr = x + (size_t)row * DMODEL;
        float4 u = ((const float4*)xr)[t];
        float v[4] = { u.x, u.y, u.z, u.w };
        float s = v[0] + v[1] + v[2] + v[3];
        float sq = v[0]*v[0] + v[1]*v[1] + v[2]*v[2] + v[3]*v[3];
        for (int off = 32; off; off >>= 1) { s += __shfl_xor(s, off); sq += __shfl_xor(sq, off); }
        int wave = t >> 6, lane = t & 63;
        if (!lane) { red[wave] = s; red[4 + wave] = sq; }
        __syncthreads();
        s = red[0] + red[1] + red[2] + red[3];
        sq = red[4] + red[5] + red[6] + red[7];
        float mean = s * (1.f / DMODEL);
        float var = (sq - (float)DMODEL * mean * mean) * (1.f / (DMODEL - 1));
        var = var < 0.f ? 0.f : var;
        float inv = a1[0] / (sqrtf(var) + 1e-6f);
        float bt = be1[0];
        uint2 ou;
        unsigned short r0 = f2b((v[0] - mean) * inv + bt);
        unsigned short r1 = f2b((v[1] - mean) * inv + bt);
        unsigned short r2 = f2b((v[2] - mean) * inv + bt);
        unsigned short r3 = f2b((v[3] - mean) * inv + bt);
        ou.x = (unsigned int)r0 | ((unsigned int)r1 << 16);
        ou.y = (unsigned int)r2 | ((unsigned int)r3 << 16);
        ((uint2*)(n1 + (size_t)row * DMODEL))[t] = ou;
    }
}

// ---------------- fused pack K + V (gather through compaction idx) ----------------
__global__ __launch_bounds__(256) void pack_kv(const unsigned short* __restrict__ Kb,
                                               const unsigned short* __restrict__ Vb,
                                               const int* __restrict__ idx,
                                               const int* __restrict__ ntiles,
                                               unsigned short* __restrict__ Kc,
                                               unsigned short* __restrict__ Vc) {
    __shared__ unsigned short tl[64 * 65];
    const int t = threadIdx.x;
    const int kt = blockIdx.x, h = blockIdx.y, b = blockIdx.z;
    if (kt >= ntiles[b]) return;
    const int* idxb = idx + b * SEQ + kt * 64;
    const unsigned short* srcK = Kb + (size_t)b * SEQ * 1024 + h * HDIM;
    unsigned short* dstK = Kc + ((size_t)((b * NHEAD + h) * 32 + kt)) * 4096;
    for (int i = 0; i < 2; i++) {
        int ci = t + 256 * i;
        int r = ci >> 3, cp = ci & 7;
        int cl = cp ^ (r & 7);
        int row = idxb[r];
        *(uint4*)&dstK[ci * 8] = *(const uint4*)&srcK[(size_t)row * 1024 + cl * 8];
    }
    const unsigned short* srcV = Vb + (size_t)b * SEQ * 1024 + h * HDIM;
    for (int i = 0; i < 16; i++) {
        int idx2 = t + 256 * i;
        int r = idx2 >> 6, c = idx2 & 63;    // r = key local, c = d
        int row = idxb[r];
        tl[r * 65 + c] = srcV[(size_t)row * 1024 + c];
    }
    __syncthreads();
    unsigned short* dstV = Vc + ((size_t)((b * NHEAD + h) * 32 + kt)) * 4096;
    for (int i = 0; i < 2; i++) {
        int ci = t + 256 * i;
        int r = ci >> 3, cp = ci & 7;        // r = d
        int cl = cp ^ (r & 7);
        ushort4 e0, e1;
        e0.x = tl[(cl * 8 + 0) * 65 + r]; e0.y = tl[(cl * 8 + 1) * 65 + r];
        e0.z = tl[(cl * 8 + 2) * 65 + r]; e0.w = tl[(cl * 8 + 3) * 65 + r];
        e1.x = tl[(cl * 8 + 4) * 65 + r]; e1.y = tl[(cl * 8 + 5) * 65 + r];
        e1.z = tl[(cl * 8 + 6) * 65 + r]; e1.w = tl[(cl * 8 + 7) * 65 + r];
        *(ushort4*)&dstV[ci * 8]     = e0;
        *(ushort4*)&dstV[ci * 8 + 4] = e1;
    }
}

// ------------- fused: h = hbuf + pbuf (write back) ; n2 = LN(h) -------------
__global__ __launch_bounds__(256) void ln_add(float* __restrict__ hb,
                                              const float* __restrict__ pbuf,
                                              const float* __restrict__ al,
                                              const float* __restrict__ be,
                                              unsigned short* __restrict__ o) {
    const int row = blockIdx.x;
    float* hr = hb + (size_t)row * DMODEL;
    const float* pr = pbuf + (size_t)row * DMODEL;
    float4 u = ((const float4*)hr)[threadIdx.x];
    float4 p = ((const float4*)pr)[threadIdx.x];
    u.x += p.x; u.y += p.y; u.z += p.z; u.w += p.w;
    ((float4*)hr)[threadIdx.x] = u;
    float v[4] = { u.x, u.y, u.z, u.w };
    float s = v[0] + v[1] + v[2] + v[3];
    float sq = v[0]*v[0] + v[1]*v[1] + v[2]*v[2] + v[3]*v[3];
    for (int off = 32; off; off >>= 1) { s += __shfl_xor(s, off); sq += __shfl_xor(sq, off); }
    __shared__ float red[8];
    int wave = threadIdx.x >> 6, lane = threadIdx.x & 63;
    if (!lane) { red[wave] = s; red[4 + wave] = sq; }
    __syncthreads();
    s = red[0] + red[1] + red[2] + red[3];
    sq = red[4] + red[5] + red[6] + red[7];
    float mean = s * (1.f / DMODEL);
    float var = (sq - (float)DMODEL * mean * mean) * (1.f / (DMODEL - 1));
    var = var < 0.f ? 0.f : var;
    float inv = al[0] / (sqrtf(var) + 1e-6f);
    float bt = be[0];
    uint2 ou;
    unsigned short r0 = f2b((v[0] - mean) * inv + bt);
    unsigned short r1 = f2b((v[1] - mean) * inv + bt);
    unsigned short r2 = f2b((v[2] - mean) * inv + bt);
    unsigned short r3 = f2b((v[3] - mean) * inv + bt);
    ou.x = (unsigned int)r0 | ((unsigned int)r1 << 16);
    ou.y = (unsigned int)r2 | ((unsigned int)r3 << 16);
    ((uint2*)(o + (size_t)row * DMODEL))[threadIdx.x] = ou;
}

// ---------------- combine: out += Pbuf ----------------
__global__ __launch_bounds__(256) void add_pbuf(float* __restrict__ out,
                                                const float* __restrict__ pbuf) {
    const int i0 = (blockIdx.x * 256 + threadIdx.x) * 8;
    float4 a0 = *(const float4*)&out[i0];
    float4 a1 = *(const float4*)&out[i0 + 4];
    float4 p0 = *(const float4*)&pbuf[i0];
    float4 p1 = *(const float4*)&pbuf[i0 + 4];
    a0.x += p0.x; a0.y += p0.y; a0.z += p0.z; a0.w += p0.w;
    a1.x += p1.x; a1.y += p1.y; a1.z += p1.z; a1.w += p1.w;
    *(float4*)&out[i0]     = a0;
    *(float4*)&out[i0 + 4] = a1;
}

// ======== gemm128k: BM=BN=128, 8 waves (2M x 2N x 2K-split), 2 blocks/CU =========
// Unified GEMM for all 4 matmuls (M=4096 always -> 32 m-panels). Flat grid with
// XCD-chunked bijective swizzle (total blocks % 8 == 0). SPLITK folds the split-K
// half into the swizzled id (z = swz&1): z=0 -> C(+bias,+res), z=1 -> pbuf raw.
// Within-block K-split waves (sW) combine through LDS at the epilogue.

__device__ __forceinline__ void stage128(const unsigned short* __restrict__ mat,
                                         int base, int K, int k0,
                                         unsigned short* sdst, int t) {
#pragma unroll
    for (int q = 0; q < 2; q++) {
        int rl = t >> 3;                    // 0..63
        int c  = (t & 7) ^ (rl & 7);        // pre-swizzled source column
        gload_lds16(mat + (size_t)(base + q * 64 + rl) * K + k0 + c * 8,
                    sdst + q * 4096 + (size_t)t * 8);
    }
}

__device__ __forceinline__ s8v rdfrag128(const unsigned short* sm, int q, int fi,
                                         int l16, int quad, int sW) {
    int rl = fi * 16 + l16;
    int p = (sW * 4 + quad) ^ (l16 & 7);
    return *(const s8v*)&sm[q * 4096 + rl * 64 + p * 8];
}

template<bool RELU, bool RES, bool SPLITK, bool SPLIT3, typename CT>
__global__ __launch_bounds__(512, 4) void gemm128k(const unsigned short* __restrict__ A,
                                                   const unsigned short* __restrict__ Bt,
                                                   const float* __restrict__ bias,
                                                   const float* __restrict__ res,
                                                   CT* __restrict__ C,
                                                   float* __restrict__ pbuf,
                                                   int M, int N, int K, int KS) {
    __shared__ __align__(16) unsigned short smem[4][8192];  // [0,1]=A dbuf, [2,3]=B dbuf
    const int t = threadIdx.x;
    const int wave = t >> 6, lane = t & 63;
    const int quad = lane >> 4, l16 = lane & 15;
    const int sW = wave >> 2, wm = (wave >> 1) & 1, wn = wave & 1;
    // flat id -> XCD-chunked bijective swizzle (total % 8 == 0)
    const int lin = blockIdx.x + blockIdx.y * gridDim.x;
    const int cpx = (gridDim.x * gridDim.y) >> 3;
    const int swz = (lin & 7) * cpx + (lin >> 3);
    int z, m0, n0;
    if constexpr (SPLITK) {
        z  = swz & 1;
        m0 = ((swz >> 1) & 31) * 128;
        n0 = (swz >> 6) * 128;
    } else {
        z  = 0;
        m0 = (swz & 31) * 128;
        n0 = (swz >> 5) * 128;
    }
    const int kbeg = z * KS;
    const int nt = KS >> 6;             // >= 2

    f4v acc[4][4] = {};

    // prologue: tiles 0,1 in flight; wait tile 0 (4 loads/thread/tile)
    stage128(A,  m0, K, kbeg,      smem[0], t);
    stage128(Bt, n0, K, kbeg,      smem[2], t);
    stage128(A,  m0, K, kbeg + 64, smem[1], t);
    stage128(Bt, n0, K, kbeg + 64, smem[3], t);
    wait_vmcnt<4>();
    __builtin_amdgcn_s_barrier();

    for (int it = 0; it < nt; ++it) {
        const int cb = it & 1;
        const unsigned short* sA = smem[cb];
        const unsigned short* sB = smem[2 + cb];
        s8v a[4], b[4];
#pragma unroll
        for (int i = 0; i < 4; i++) a[i] = rdfrag128(sA, wm, i, l16, quad, sW);
#pragma unroll
        for (int i = 0; i < 4; i++) b[i] = rdfrag128(sB, wn, i, l16, quad, sW);
        __builtin_amdgcn_s_setprio(1);
#pragma unroll
        for (int mi = 0; mi < 4; mi++)
#pragma unroll
            for (int ni = 0; ni < 4; ni++)
                acc[mi][ni] = mfma_bf16(a[mi], b[ni], acc[mi][ni]);
        __builtin_amdgcn_s_setprio(0);
        asm volatile("s_waitcnt lgkmcnt(0)" ::: "memory");  // reads drained (free by now)
        __builtin_amdgcn_s_barrier();       // all waves done reading buf cb
        if (it + 2 < nt) {
            stage128(A,  m0, K, kbeg + (it + 2) * 64, smem[cb], t);
            stage128(Bt, n0, K, kbeg + (it + 2) * 64, smem[2 + cb], t);
            wait_vmcnt<4>();                // tile it+1 landed; it+2 in flight
        } else if (it + 1 < nt) {
            wait_vmcnt<0>();                // last tile landed
        }
        __builtin_amdgcn_s_barrier();       // publish tile it+1
    }

    // combine the two K-split halves: sW=1 exports acc via LDS; sW=0 adds + writes
    float* xch = (float*)&smem[0][0];
    float* myx = xch + (wm * 2 + wn) * 4096;    // 16 KB per pair, 64 KB total
    if (sW == 1) {
#pragma unroll
        for (int mi = 0; mi < 4; mi++)
#pragma unroll
            for (int ni = 0; ni < 4; ni++)
                *(f4v*)&myx[(mi * 4 + ni) * 256 + lane * 4] = acc[mi][ni];
    }
    __builtin_amdgcn_s_barrier();
    if (sW == 0) {
#pragma unroll
        for (int mi = 0; mi < 4; mi++)
#pragma unroll
            for (int ni = 0; ni < 4; ni++)
                acc[mi][ni] += *(const f4v*)&myx[(mi * 4 + ni) * 256 + lane * 4];
#pragma unroll
        for (int mi = 0; mi < 4; mi++)
#pragma unroll
            for (int ni = 0; ni < 4; ni++) {
                const int col = n0 + wn * 64 + ni * 16 + l16;
                const int row0 = m0 + wm * 64 + mi * 16 + quad * 4;
                if (!SPLITK || z == 0) {
                    const float bv = bias[col];
#pragma unroll
                    for (int r = 0; r < 4; r++) {
                        float v = acc[mi][ni][r] + bv;
                        if (RELU) v = v > 0.f ? v : 0.f;
                        if (RES) v += res[(size_t)(row0 + r) * N + col];
                        size_t ix;
                        if constexpr (SPLIT3)
                            ix = (size_t)(col >> 10) * ((size_t)NTOK * 1024)
                               + (size_t)(row0 + r) * 1024 + (col & 1023);
                        else
                            ix = (size_t)(row0 + r) * N + col;
                        if constexpr (sizeof(CT) == 2)
                            C[ix] = f2b(v);
                        else
                            C[ix] = v;
                    }
                } else {
#pragma unroll
                    for (int r = 0; r < 4; r++)
                        pbuf[(size_t)(row0 + r) * N + col] = acc[mi][ni][r];
                }
            }
    }
}

// ============ flash attention v3: compacted keys, 128 q/block, dbuf, exp2 softmax ========
#define EXPC 0.18033688f   // 0.125 * log2(e)
__device__ __forceinline__ void attn_tile(const unsigned short* __restrict__ smKb,
                                          const unsigned short* __restrict__ smVb,
                                          const float* __restrict__ smM, int k0,
                                          unsigned short* __restrict__ smPw,
                                          s8v qf0, s8v qf1, int quad, int l16,
                                          float& l_s, f4v* oacc) {
    const int l7 = l16 & 7;
    f4v s[4];
#pragma unroll
    for (int kt4 = 0; kt4 < 4; kt4++) {
        int r = kt4 * 16 + l16;
        s8v kf0 = *(const s8v*)&smKb[r * 64 + ((quad ^ l7) * 8)];
        s8v kf1 = *(const s8v*)&smKb[r * 64 + (((quad + 4) ^ l7) * 8)];
        f4v z = {};
        z = mfma_bf16(kf0, qf0, z);
        z = mfma_bf16(kf1, qf1, z);
        s[kt4] = z;
    }
#pragma unroll
    for (int kt4 = 0; kt4 < 4; kt4++) {
        float4 mf = *(const float4*)&smM[k0 + kt4 * 16 + quad * 4];
        s[kt4][0] = s[kt4][0] * EXPC + mf.x;
        s[kt4][1] = s[kt4][1] * EXPC + mf.y;
        s[kt4][2] = s[kt4][2] * EXPC + mf.z;
        s[kt4][3] = s[kt4][3] * EXPC + mf.w;
    }
#pragma unroll
    for (int kt4 = 0; kt4 < 4; kt4++)
#pragma unroll
        for (int r = 0; r < 4; r++) {
            float p = __builtin_amdgcn_exp2f(s[kt4][r]);
            s[kt4][r] = p;
            l_s += p;
        }
#pragma unroll
    for (int kt4 = 0; kt4 < 4; kt4++) {
        ushort2 p01 = cvt_pk(s[kt4][0], s[kt4][1]);
        ushort2 p23 = cvt_pk(s[kt4][2], s[kt4][3]);
        ushort4 pk;
        pk.x = p01.x; pk.y = p01.y; pk.z = p23.x; pk.w = p23.y;
        int c = kt4 * 2 + (quad >> 1);
        *(ushort4*)&smPw[l16 * 64 + ((c ^ l7) * 8 + (quad & 1) * 4)] = pk;
    }
    s8v pf0 = *(const s8v*)&smPw[l16 * 64 + ((quad ^ l7) * 8)];
    s8v pf1 = *(const s8v*)&smPw[l16 * 64 + (((quad + 4) ^ l7) * 8)];
#pragma unroll
    for (int nt = 0; nt < 4; nt++) {
        int r = nt * 16 + l16;
        s8v v0 = *(const s8v*)&smVb[r * 64 + ((quad ^ l7) * 8)];
        s8v v1 = *(const s8v*)&smVb[r * 64 + (((quad + 4) ^ l7) * 8)];
        oacc[nt] = mfma_bf16(pf0, v0, oacc[nt]);
        oacc[nt] = mfma_bf16(pf1, v1, oacc[nt]);
    }
}

__global__ __launch_bounds__(512) void attn_kernel(const unsigned short* __restrict__ Qb,
                                                   const unsigned short* __restrict__ Kc,
                                                   const unsigned short* __restrict__ Vc,
                                                   const float* __restrict__ maskc2,
                                                   const int* __restrict__ ntiles,
                                                   unsigned short* __restrict__ out) {
    __shared__ __align__(16) unsigned short smK[2][4096];   // 64 keys x 64 d, swizzled
    __shared__ __align__(16) unsigned short smV[2][4096];   // 64 d x 64 keys, swizzled
    __shared__ __align__(16) unsigned short smP[8][1024];   // per-wave P, swizzled stride 64
    __shared__ __align__(16) float smM[SEQ];                // compacted mask row (pads=-1e9)

    const int t = threadIdx.x;
    const int wave = t >> 6, lane = t & 63;
    const int quad = lane >> 4, l16 = lane & 15;
    // XCD-chunked swizzle (512 blocks): each XCD gets 4 (b,h) groups' K/V (L2-resident)
    const int lin = blockIdx.x + (blockIdx.y << 4) + (blockIdx.z << 8);
    const int swz = (lin & 7) * 64 + (lin >> 3);
    const int qt = swz & 15, h = (swz >> 4) & 15, b = swz >> 8;
    const int q0 = qt * 128 + wave * 16;
    const int nt = ntiles[b];
    const unsigned short* Kbh = Kc + ((size_t)(b * NHEAD + h)) * 32 * 4096;
    const unsigned short* Vbh = Vc + ((size_t)(b * NHEAD + h)) * 32 * 4096;
    unsigned short* smPw = &smP[wave][0];

    const unsigned short* Qp = Qb + ((size_t)b * SEQ + q0 + l16) * 1024 + h * HDIM + quad * 8;
    s8v qf0 = *(const s8v*)(Qp);
    s8v qf1 = *(const s8v*)(Qp + 32);

    gload_lds16(maskc2 + (size_t)b * SEQ + t * 4, (float*)smM + t * 4);
    gload_lds16(Kbh + t * 8,        smK[0] + t * 8);
    gload_lds16(Vbh + t * 8,        smV[0] + t * 8);
    gload_lds16(Kbh + 4096 + t * 8, smK[1] + t * 8);
    gload_lds16(Vbh + 4096 + t * 8, smV[1] + t * 8);
    wait_vmcnt<2>();
    __builtin_amdgcn_s_barrier();

    float l_s = 0.f;
    f4v oacc[4] = {};

    for (int it = 0; it < nt; ++it) {
        const int cb = it & 1;
        __builtin_amdgcn_s_setprio(1);
        attn_tile(smK[cb], smV[cb], smM, it * 64, smPw, qf0, qf1, quad, l16, l_s, oacc);
        __builtin_amdgcn_s_setprio(0);
        if (it + 2 < nt) {
            asm volatile("s_waitcnt lgkmcnt(0)" ::: "memory");
            __builtin_amdgcn_s_barrier();
            gload_lds16(Kbh + (size_t)(it + 2) * 4096 + t * 8, smK[cb] + t * 8);
            gload_lds16(Vbh + (size_t)(it + 2) * 4096 + t * 8, smV[cb] + t * 8);
            wait_vmcnt<2>();
            __builtin_amdgcn_s_barrier();
        } else if (it + 1 < nt) {
            asm volatile("s_waitcnt lgkmcnt(0)" ::: "memory");
            __builtin_amdgcn_s_barrier();
            wait_vmcnt<0>();
            __builtin_amdgcn_s_barrier();
        }
    }

    l_s += __shfl_xor(l_s, 16);
    l_s += __shfl_xor(l_s, 32);
    float lrr[4];
    for (int r = 0; r < 4; r++) lrr[r] = __shfl(l_s, quad * 4 + r);
    for (int nt2 = 0; nt2 < 4; nt2++)
        for (int r = 0; r < 4; r++) {
            int row = q0 + quad * 4 + r;
            int col = h * HDIM + nt2 * 16 + l16;
            out[((size_t)b * SEQ + row) * DMODEL + col] = f2b(oacc[nt2][r] / lrr[r]);
        }
}

extern "C" void kernel_launch(void* const* d_in, const int* in_sizes, int n_in,
                              void* d_out, int out_size, void* d_ws, size_t ws_size,
                              hipStream_t stream) {
    const float* x   = (const float*)d_in[0];
    const int*   msk = (const int*)d_in[1];
    const float* Wq  = (const float*)d_in[2];
    const float* bq  = (const float*)d_in[3];
    const float* Wk  = (const float*)d_in[4];
    const float* bk  = (const float*)d_in[5];
    const float* Wv  = (const float*)d_in[6];
    const float* bv  = (const float*)d_in[7];
    const float* Wo  = (const float*)d_in[8];
    const float* bo  = (const float*)d_in[9];
    const float* W1  = (const float*)d_in[10];
    const float* b1  = (const float*)d_in[11];
    const float* W2  = (const float*)d_in[12];
    const float* b2  = (const float*)d_in[13];
    const float* a1  = (const float*)d_in[14];
    const float* be1 = (const float*)d_in[15];
    const float* a2  = (const float*)d_in[16];
    const float* be2 = (const float*)d_in[17];
    float* outf = (float*)d_out;   // 4096x1024 fp32 = 16 MB

    // ---- arena (R5 layout: ws + d_out reuse) ----
    char* ws = (char*)d_ws;
    const size_t MB = 1024 * 1024;
    unsigned short* W2_t   = (unsigned short*)(ws);
    unsigned short* W1_t   = (unsigned short*)(ws + 8 * MB);
    float*          Pbuf   = (float*)(ws + 8 * MB);
    unsigned short* Wqkv_t = (unsigned short*)(ws + 16 * MB);
    float*          bqkv   = (float*)(ws + 22 * MB);
    unsigned short* Kc     = (unsigned short*)(ws + 16 * MB);
    unsigned short* n2     = (unsigned short*)(ws + 16 * MB);
    unsigned short* Wo_t   = (unsigned short*)(ws + 24 * MB);
    unsigned short* Qb     = (unsigned short*)(ws + 26 * MB);
    unsigned short* Kb     = (unsigned short*)(ws + 34 * MB);
    unsigned short* Vb     = (unsigned short*)(ws + 42 * MB);
    float*          Pbuf2  = (float*)(ws + 34 * MB);   // 16 MB over dead Kb/Vb (phase 5)
    unsigned short* ff1    = (unsigned short*)(ws + 26 * MB);
    unsigned short* attnO  = (unsigned short*)(ws + 50 * MB);
    unsigned short* n1     = (unsigned short*)d_out;                 // [0,8) MB, ph1-3
    unsigned short* Vc     = (unsigned short*)d_out;                 // [0,8) MB, ph3.5-4
    float*          hbuf   = (float*)d_out;                          // 16 MB, ph5-9
    float*          maskc2 = (float*)((char*)d_out + 8 * MB);            // 16 KB
    int*            idxc   = (int*)((char*)d_out + 8 * MB + 16 * 1024);  // 16 KB
    int*            ntl    = (int*)((char*)d_out + 8 * MB + 32 * 1024);  // 8 B

    // phase 1: weight transposes + bias concat + LN1 + mask scan (z=22), single launch
    prep_weights<<<dim3(16, 16, 23), 256, 0, stream>>>(
        Wq, Wk, Wv, Wo, W1, W2, bq, bk, bv, x, a1, be1, msk,
        Wqkv_t, Wo_t, W1_t, W2_t, bqkv, n1, idxc, maskc2, ntl);

    // phase 3: [Q|K|V] = n1 @ Wqkv + bias (gemm128k, SPLIT3, 768 blocks)
    gemm128k<false, false, false, true, unsigned short><<<dim3(32, 24), 512, 0, stream>>>(
        n1, Wqkv_t, bqkv, nullptr, Qb, nullptr, NTOK, 3072, 1024, 1024);
    // phase 3.5: pack compacted K/V (Kb/Vb die here)
    pack_kv<<<dim3(32, 16, 2), 256, 0, stream>>>(Kb, Vb, idxc, ntl, Kc, Vc);
    // phase 4: attention over compacted keys (XCD-swizzled)
    attn_kernel<<<dim3(16, 16, 2), 512, 0, stream>>>(Qb, Kc, Vc, maskc2, ntl, attnO);
    // phase 5: h = x + attnO @ Wo^T + bo (gemm128k split-K=2)
    gemm128k<false, true, true, false, float><<<dim3(64, 8), 512, 0, stream>>>(
        attnO, Wo_t, bo, x, hbuf, Pbuf2, NTOK, 1024, 1024, 512);
    // phase 6: h += Pbuf2 (write back) ; n2 = LN2(h)  (fused)
    ln_add<<<NTOK, 256, 0, stream>>>(hbuf, Pbuf2, a2, be2, n2);
    // phase 7: ff1 = relu(n2 @ W1 + b1) (gemm128k, 1024 blocks)
    gemm128k<true, false, false, false, unsigned short><<<dim3(32, 32), 512, 0, stream>>>(
        n2, W1_t, b1, nullptr, ff1, nullptr, NTOK, 4096, 1024, 1024);
    // phase 8: ff2 (gemm128k split-K=2: z=0 -> out = h + b2 + acc, z=1 -> Pbuf)
    gemm128k<false, true, true, false, float><<<dim3(64, 8), 512, 0, stream>>>(
        ff1, W2_t, b2, hbuf, outf, Pbuf, NTOK, 1024, 4096, 2048);
    // phase 9: out += Pbuf
    add_pbuf<<<dim3(2048), 256, 0, stream>>>(outf, Pbuf);
}

// Round 11
// 324.825 us; speedup vs baseline: 1.0688x; 1.0688x over previous
//
#include <hip/hip_runtime.h>
#include <hip/hip_bf16.h>

#define SEQ   2048
#define BATCH 2
#define DMODEL 1024
#define DFF   4096
#define NHEAD 16
#define HDIM  64
#define NTOK  (BATCH*SEQ)   // 4096

typedef short s8v __attribute__((ext_vector_type(8)));
typedef float f4v __attribute__((ext_vector_type(4)));

__device__ __forceinline__ float b2f(unsigned short u) {
    union { unsigned int i; float f; } v; v.i = ((unsigned int)u) << 16; return v.f;
}
__device__ __forceinline__ unsigned short f2b(float f) {
    union { unsigned int i; float f; } v; v.f = f;
    unsigned int r = v.i + 0x7FFFu + ((v.i >> 16) & 1u);
    return (unsigned short)(r >> 16);
}
__device__ __forceinline__ ushort2 cvt_pk(float a, float b) {
    __hip_bfloat162 h = __float22bfloat162_rn(float2{ a, b });   // RNE, same as f2b
    return *(ushort2*)&h;
}

__device__ __forceinline__ f4v mfma_bf16(s8v a, s8v b, f4v c) {
    return __builtin_amdgcn_mfma_f32_16x16x32_bf16(a, b, c, 0, 0, 0);
}

__device__ __forceinline__ void gload_lds16(const void* g, void* l) {
    __builtin_amdgcn_global_load_lds(
        (const __attribute__((address_space(1))) unsigned int*)g,
        (__attribute__((address_space(3))) unsigned int*)l, 16, 0, 0);
}

template<int N> __device__ __forceinline__ void wait_vmcnt() {
    if constexpr (N == 8)      asm volatile("s_waitcnt vmcnt(8)" ::: "memory");
    else if constexpr (N == 6) asm volatile("s_waitcnt vmcnt(6)" ::: "memory");
    else if constexpr (N == 4) asm volatile("s_waitcnt vmcnt(4)" ::: "memory");
    else if constexpr (N == 2) asm volatile("s_waitcnt vmcnt(2)" ::: "memory");
    else                       asm volatile("s_waitcnt vmcnt(0)" ::: "memory");
}

// ---------------- one tile of fp32->bf16 transpose (vectorized) ----------------
__device__ __forceinline__ void tp_tile(const float* __restrict__ src,
                                        unsigned short* __restrict__ dst,
                                        int R, int C, int br, int bc, int t,
                                        unsigned short* tl) {
    for (int i = 0; i < 4; i++) {
        int lin = i * 1024 + t * 4;
        int r = lin >> 6, c = lin & 63;
        float4 u = *(const float4*)&src[(size_t)(br * 64 + r) * C + bc * 64 + c];
        tl[r * 65 + c + 0] = f2b(u.x);
        tl[r * 65 + c + 1] = f2b(u.y);
        tl[r * 65 + c + 2] = f2b(u.z);
        tl[r * 65 + c + 3] = f2b(u.w);
    }
    __syncthreads();
    for (int i = 0; i < 4; i++) {
        int lin = i * 1024 + t * 4;
        int r2 = lin >> 6, c2 = lin & 63;
        ushort4 o;
        o.x = tl[(c2 + 0) * 65 + r2];
        o.y = tl[(c2 + 1) * 65 + r2];
        o.z = tl[(c2 + 2) * 65 + r2];
        o.w = tl[(c2 + 3) * 65 + r2];
        *(ushort4*)&dst[(size_t)(bc * 64 + r2) * R + br * 64 + c2] = o;
    }
}

// ---------------- fused prep: weight transposes + bias concat + LN1 ------------
__global__ __launch_bounds__(256) void prep_weights(const float* __restrict__ Wq,
                                                    const float* __restrict__ Wk,
                                                    const float* __restrict__ Wv,
                                                    const float* __restrict__ Wo,
                                                    const float* __restrict__ W1,
                                                    const float* __restrict__ W2,
                                                    const float* __restrict__ bq,
                                                    const float* __restrict__ bk,
                                                    const float* __restrict__ bv,
                                                    const float* __restrict__ x,
                                                    const float* __restrict__ a1,
                                                    const float* __restrict__ be1,
                                                    unsigned short* __restrict__ Wqkv_t,
                                                    unsigned short* __restrict__ Wo_t,
                                                    unsigned short* __restrict__ W1_t,
                                                    unsigned short* __restrict__ W2_t,
                                                    float* __restrict__ bqkv,
                                                    unsigned short* __restrict__ n1) {
    __shared__ unsigned short tl[64 * 65];
    __shared__ float red[8];
    const int t = threadIdx.x;
    const int bx = blockIdx.x, by = blockIdx.y, z = blockIdx.z;
    if (z < 4) {
        const float* src = (z == 0) ? Wq : (z == 1) ? Wk : (z == 2) ? Wv : Wo;
        unsigned short* dst = (z == 3) ? Wo_t : Wqkv_t + (size_t)z * 1024 * 1024;
        tp_tile(src, dst, 1024, 1024, bx, by, t, tl);
    } else if (z == 4) {
        for (int i = 0; i < 4; i++) {
            tp_tile(W1, W1_t, 1024, 4096, bx, by + 16 * i, t, tl);
            __syncthreads();
        }
    } else if (z == 5) {
        if (bx == 0 && by == 0) {
            for (int i = 0; i < 12; i++) {
                int idx = t + 256 * i;
                if (idx < 1024) bqkv[idx] = bq[idx];
                else if (idx < 2048) bqkv[idx] = bk[idx - 1024];
                else if (idx < 3072) bqkv[idx] = bv[idx - 2048];
            }
        }
        for (int i = 0; i < 4; i++) {
            tp_tile(W2, W2_t, 4096, 1024, bx + 16 * i, by, t, tl);
            __syncthreads();
        }
    } else {
        // LN1: one row per block
        const int row = (z - 6) * 256 + by * 16 + bx;
        const float* xr = x + (size_t)row * DMODEL;
        float4 u = ((const float4*)xr)[t];
        float v[4] = { u.x, u.y, u.z, u.w };
        float s = v[0] + v[1] + v[2] + v[3];
        float sq = v[0]*v[0] + v[1]*v[1] + v[2]*v[2] + v[3]*v[3];
        for (int off = 32; off; off >>= 1) { s += __shfl_xor(s, off); sq += __shfl_xor(sq, off); }
        int wave = t >> 6, lane = t & 63;
        if (!lane) { red[wave] = s; red[4 + wave] = sq; }
        __syncthreads();
        s = red[0] + red[1] + red[2] + red[3];
        sq = red[4] + red[5] + red[6] + red[7];
        float mean = s * (1.f / DMODEL);
        float var = (sq - (float)DMODEL * mean * mean) * (1.f / (DMODEL - 1));
        var = var < 0.f ? 0.f : var;
        float inv = a1[0] / (sqrtf(var) + 1e-6f);
        float bt = be1[0];
        uint2 ou;
        unsigned short r0 = f2b((v[0] - mean) * inv + bt);
        unsigned short r1 = f2b((v[1] - mean) * inv + bt);
        unsigned short r2 = f2b((v[2] - mean) * inv + bt);
        unsigned short r3 = f2b((v[3] - mean) * inv + bt);
        ou.x = (unsigned int)r0 | ((unsigned int)r1 << 16);
        ou.y = (unsigned int)r2 | ((unsigned int)r3 << 16);
        ((uint2*)(n1 + (size_t)row * DMODEL))[t] = ou;
    }
}

// -------- mask scan: per-batch compaction of unmasked keys (prob of masked key == 0) ----
__global__ __launch_bounds__(256) void mask_scan(const int* __restrict__ msk,
                                                 int* __restrict__ idx,
                                                 float* __restrict__ maskc2,
                                                 int* __restrict__ ntiles) {
    const int b = blockIdx.x, t = threadIdx.x;
    const int base = b * SEQ;
    __shared__ int wsum[4];
    int k[8]; int cnt = 0;
    for (int j = 0; j < 8; j++) {
        k[j] = (msk[base + t * 8 + j] != 0) ? 1 : 0;
        cnt += k[j];
    }
    const int lane = t & 63, wv = t >> 6;
    int pre = cnt;
    for (int off = 1; off < 64; off <<= 1) {
        int n = __shfl_up(pre, off);
        if (lane >= off) pre += n;
    }
    if (lane == 63) wsum[wv] = pre;
    __syncthreads();
    const int Nb = wsum[0] + wsum[1] + wsum[2] + wsum[3];
    int woff = 0;
    for (int w = 0; w < wv; w++) woff += wsum[w];
    const int excl = woff + pre - cnt;
    for (int j = 0; j < 8; j++) {
        int g = t * 8 + j;
        idx[base + g] = 0;
        maskc2[base + g] = (g < Nb) ? 0.f : -1e9f;
    }
    __syncthreads();
    int pos = excl;
    for (int j = 0; j < 8; j++) {
        if (k[j]) { idx[base + pos] = t * 8 + j; pos++; }
    }
    if (t == 0) ntiles[b] = (Nb + 63) >> 6;
}

// ---------------- fused pack K + V (gather through compaction idx) ----------------
__global__ __launch_bounds__(256) void pack_kv(const unsigned short* __restrict__ Kb,
                                               const unsigned short* __restrict__ Vb,
                                               const int* __restrict__ idx,
                                               const int* __restrict__ ntiles,
                                               unsigned short* __restrict__ Kc,
                                               unsigned short* __restrict__ Vc) {
    __shared__ unsigned short tl[64 * 65];
    const int t = threadIdx.x;
    const int kt = blockIdx.x, h = blockIdx.y, b = blockIdx.z;
    if (kt >= ntiles[b]) return;
    const int* idxb = idx + b * SEQ + kt * 64;
    const unsigned short* srcK = Kb + (size_t)b * SEQ * 1024 + h * HDIM;
    unsigned short* dstK = Kc + ((size_t)((b * NHEAD + h) * 32 + kt)) * 4096;
    for (int i = 0; i < 2; i++) {
        int ci = t + 256 * i;
        int r = ci >> 3, cp = ci & 7;
        int cl = cp ^ (r & 7);
        int row = idxb[r];
        *(uint4*)&dstK[ci * 8] = *(const uint4*)&srcK[(size_t)row * 1024 + cl * 8];
    }
    const unsigned short* srcV = Vb + (size_t)b * SEQ * 1024 + h * HDIM;
    for (int i = 0; i < 16; i++) {
        int idx2 = t + 256 * i;
        int r = idx2 >> 6, c = idx2 & 63;    // r = key local, c = d
        int row = idxb[r];
        tl[r * 65 + c] = srcV[(size_t)row * 1024 + c];
    }
    __syncthreads();
    unsigned short* dstV = Vc + ((size_t)((b * NHEAD + h) * 32 + kt)) * 4096;
    for (int i = 0; i < 2; i++) {
        int ci = t + 256 * i;
        int r = ci >> 3, cp = ci & 7;        // r = d
        int cl = cp ^ (r & 7);
        ushort4 e0, e1;
        e0.x = tl[(cl * 8 + 0) * 65 + r]; e0.y = tl[(cl * 8 + 1) * 65 + r];
        e0.z = tl[(cl * 8 + 2) * 65 + r]; e0.w = tl[(cl * 8 + 3) * 65 + r];
        e1.x = tl[(cl * 8 + 4) * 65 + r]; e1.y = tl[(cl * 8 + 5) * 65 + r];
        e1.z = tl[(cl * 8 + 6) * 65 + r]; e1.w = tl[(cl * 8 + 7) * 65 + r];
        *(ushort4*)&dstV[ci * 8]     = e0;
        *(ushort4*)&dstV[ci * 8 + 4] = e1;
    }
}

// ------------- fused: h = hbuf + pbuf (write back) ; n2 = LN(h) -------------
__global__ __launch_bounds__(256) void ln_add(float* __restrict__ hb,
                                              const float* __restrict__ pbuf,
                                              const float* __restrict__ al,
                                              const float* __restrict__ be,
                                              unsigned short* __restrict__ o) {
    const int row = blockIdx.x;
    float* hr = hb + (size_t)row * DMODEL;
    const float* pr = pbuf + (size_t)row * DMODEL;
    float4 u = ((const float4*)hr)[threadIdx.x];
    float4 p = ((const float4*)pr)[threadIdx.x];
    u.x += p.x; u.y += p.y; u.z += p.z; u.w += p.w;
    ((float4*)hr)[threadIdx.x] = u;
    float v[4] = { u.x, u.y, u.z, u.w };
    float s = v[0] + v[1] + v[2] + v[3];
    float sq = v[0]*v[0] + v[1]*v[1] + v[2]*v[2] + v[3]*v[3];
    for (int off = 32; off; off >>= 1) { s += __shfl_xor(s, off); sq += __shfl_xor(sq, off); }
    __shared__ float red[8];
    int wave = threadIdx.x >> 6, lane = threadIdx.x & 63;
    if (!lane) { red[wave] = s; red[4 + wave] = sq; }
    __syncthreads();
    s = red[0] + red[1] + red[2] + red[3];
    sq = red[4] + red[5] + red[6] + red[7];
    float mean = s * (1.f / DMODEL);
    float var = (sq - (float)DMODEL * mean * mean) * (1.f / (DMODEL - 1));
    var = var < 0.f ? 0.f : var;
    float inv = al[0] / (sqrtf(var) + 1e-6f);
    float bt = be[0];
    uint2 ou;
    unsigned short r0 = f2b((v[0] - mean) * inv + bt);
    unsigned short r1 = f2b((v[1] - mean) * inv + bt);
    unsigned short r2 = f2b((v[2] - mean) * inv + bt);
    unsigned short r3 = f2b((v[3] - mean) * inv + bt);
    ou.x = (unsigned int)r0 | ((unsigned int)r1 << 16);
    ou.y = (unsigned int)r2 | ((unsigned int)r3 << 16);
    ((uint2*)(o + (size_t)row * DMODEL))[threadIdx.x] = ou;
}

// ---------------- combine: out += Pbuf ----------------
__global__ __launch_bounds__(256) void add_pbuf(float* __restrict__ out,
                                                const float* __restrict__ pbuf) {
    const int i0 = (blockIdx.x * 256 + threadIdx.x) * 8;
    float4 a0 = *(const float4*)&out[i0];
    float4 a1 = *(const float4*)&out[i0 + 4];
    float4 p0 = *(const float4*)&pbuf[i0];
    float4 p1 = *(const float4*)&pbuf[i0 + 4];
    a0.x += p0.x; a0.y += p0.y; a0.z += p0.z; a0.w += p0.w;
    a1.x += p1.x; a1.y += p1.y; a1.z += p1.z; a1.w += p1.w;
    *(float4*)&out[i0]     = a0;
    *(float4*)&out[i0 + 4] = a1;
}

// ================= 256x256 8-phase pipelined GEMM (T2+T3+T4+T5, m201 schedule) ========
template<int SPAN, int NL>
__device__ __forceinline__ void stage_half(const unsigned short* __restrict__ mat,
                                           int base, int K, int k0, int q,
                                           unsigned short* sdst, int t) {
#pragma unroll
    for (int i = 0; i < NL; i++) {
        int ci = i * 512 + t;
        int rl = ci >> 3;
        int c  = (ci & 7) ^ (rl & 7);                      // pre-swizzled source column
        int gr = (rl / SPAN) * (2 * SPAN) + q * SPAN + (rl % SPAN);
        gload_lds16(mat + (size_t)(base + gr) * K + k0 + c * 8, sdst + (size_t)ci * 8);
    }
}

__device__ __forceinline__ const s8v* afrag(const unsigned short* sA, int mi, int s,
                                            int wm, int l16, int quad) {
    int q = mi >> 2;
    int rl = wm * 64 + (mi & 3) * 16 + l16;
    return (const s8v*)&sA[q * 8192 + rl * 64 + (((s * 4 + quad) ^ (l16 & 7)) * 8)];
}
__device__ __forceinline__ const s8v* bfrag(const unsigned short* sB, int ni, int s,
                                            int wn, int l16, int quad) {
    int q = ni >> 1;
    int rl = wn * 32 + (ni & 1) * 16 + l16;
    return (const s8v*)&sB[q * 8192 + rl * 64 + (((s * 4 + quad) ^ (l16 & 7)) * 8)];
}

__device__ __forceinline__ void half_8ph(const unsigned short* __restrict__ A,
                                         const unsigned short* __restrict__ Bt,
                                         int m0, int n0, int K, int kT1, int kT2, bool doT2,
                                         const unsigned short* sAr, const unsigned short* sBr,
                                         unsigned short* sA_this, unsigned short* sB_this,
                                         unsigned short* sA_oth,
                                         int wm, int wn, int l16, int quad, int t,
                                         f4v acc[8][4]) {
    s8v a[4][2], b[4][2];
    // ---- phase a: Q(0,0) ----
#pragma unroll
    for (int m2 = 0; m2 < 4; m2++) {
        a[m2][0] = *afrag(sAr, m2, 0, wm, l16, quad);
        a[m2][1] = *afrag(sAr, m2, 1, wm, l16, quad);
    }
#pragma unroll
    for (int nb = 0; nb < 2; nb++) {
        b[nb][0] = *bfrag(sBr, nb, 0, wn, l16, quad);
        b[nb][1] = *bfrag(sBr, nb, 1, wn, l16, quad);
    }
    stage_half<64, 2>(A, m0, K, kT1, 1, sA_oth + 8192, t);
    __builtin_amdgcn_s_barrier();
    asm volatile("s_waitcnt lgkmcnt(0)" ::: "memory");
    __builtin_amdgcn_s_setprio(1);
#pragma unroll
    for (int m2 = 0; m2 < 4; m2++)
#pragma unroll
        for (int nb = 0; nb < 2; nb++) {
            acc[m2][nb] = mfma_bf16(a[m2][0], b[nb][0], acc[m2][nb]);
            acc[m2][nb] = mfma_bf16(a[m2][1], b[nb][1], acc[m2][nb]);
        }
    __builtin_amdgcn_s_setprio(0);
    __builtin_amdgcn_s_barrier();
    // ---- phase b: Q(0,1) ----
#pragma unroll
    for (int nb = 0; nb < 2; nb++) {
        b[2 + nb][0] = *bfrag(sBr, 2 + nb, 0, wn, l16, quad);
        b[2 + nb][1] = *bfrag(sBr, 2 + nb, 1, wn, l16, quad);
    }
    if (doT2) stage_half<64, 2>(A, m0, K, kT2, 0, sA_this, t);
    __builtin_amdgcn_s_barrier();
    asm volatile("s_waitcnt lgkmcnt(0)" ::: "memory");
    __builtin_amdgcn_s_setprio(1);
#pragma unroll
    for (int m2 = 0; m2 < 4; m2++)
#pragma unroll
        for (int nb = 0; nb < 2; nb++) {
            acc[m2][2 + nb] = mfma_bf16(a[m2][0], b[2 + nb][0], acc[m2][2 + nb]);
            acc[m2][2 + nb] = mfma_bf16(a[m2][1], b[2 + nb][1], acc[m2][2 + nb]);
        }
    __builtin_amdgcn_s_setprio(0);
    __builtin_amdgcn_s_barrier();
    // ---- phase c: Q(1,0) ----
#pragma unroll
    for (int m2 = 0; m2 < 4; m2++) {
        a[m2][0] = *afrag(sAr, 4 + m2, 0, wm, l16, quad);
        a[m2][1] = *afrag(sAr, 4 + m2, 1, wm, l16, quad);
    }
    if (doT2) stage_half<32, 2>(Bt, n0, K, kT2, 0, sB_this, t);
    __builtin_amdgcn_s_barrier();
    asm volatile("s_waitcnt lgkmcnt(0)" ::: "memory");
    __builtin_amdgcn_s_setprio(1);
#pragma unroll
    for (int m2 = 0; m2 < 4; m2++)
#pragma unroll
        for (int nb = 0; nb < 2; nb++) {
            acc[4 + m2][nb] = mfma_bf16(a[m2][0], b[nb][0], acc[4 + m2][nb]);
            acc[4 + m2][nb] = mfma_bf16(a[m2][1], b[nb][1], acc[4 + m2][nb]);
        }
    __builtin_amdgcn_s_setprio(0);
    __builtin_amdgcn_s_barrier();
    // ---- phase d: Q(1,1) ----
    if (doT2) {
        stage_half<32, 2>(Bt, n0, K, kT2, 1, sB_this + 8192, t);
        wait_vmcnt<6>();
    } else {
        wait_vmcnt<0>();
    }
    __builtin_amdgcn_s_barrier();
    __builtin_amdgcn_s_setprio(1);
#pragma unroll
    for (int m2 = 0; m2 < 4; m2++)
#pragma unroll
        for (int nb = 0; nb < 2; nb++) {
            acc[4 + m2][2 + nb] = mfma_bf16(a[m2][0], b[2 + nb][0], acc[4 + m2][2 + nb]);
            acc[4 + m2][2 + nb] = mfma_bf16(a[m2][1], b[2 + nb][1], acc[4 + m2][2 + nb]);
        }
    __builtin_amdgcn_s_setprio(0);
    __builtin_amdgcn_s_barrier();
}

__device__ __forceinline__ void comp_full(const unsigned short* sA, const unsigned short* sB,
                                          int wm, int wn, int l16, int quad,
                                          f4v acc[8][4]) {
    s8v b[4][2];
#pragma unroll
    for (int ni = 0; ni < 4; ni++) {
        b[ni][0] = *bfrag(sB, ni, 0, wn, l16, quad);
        b[ni][1] = *bfrag(sB, ni, 1, wn, l16, quad);
    }
#pragma unroll
    for (int mi = 0; mi < 8; mi++) {
        s8v a0 = *afrag(sA, mi, 0, wm, l16, quad);
        s8v a1 = *afrag(sA, mi, 1, wm, l16, quad);
#pragma unroll
        for (int ni = 0; ni < 4; ni++) {
            acc[mi][ni] = mfma_bf16(a0, b[ni][0], acc[mi][ni]);
            acc[mi][ni] = mfma_bf16(a1, b[ni][1], acc[mi][ni]);
        }
    }
}

template<bool RELU, typename CT, bool SPLIT3>
__global__ __launch_bounds__(512, 2) void gemm256(const unsigned short* __restrict__ A,
                                                  const unsigned short* __restrict__ Bt,
                                                  const float* __restrict__ bias,
                                                  CT* __restrict__ C,
                                                  int M, int N, int K) {
    __shared__ __align__(16) unsigned short smA[2][256 * 64];
    __shared__ __align__(16) unsigned short smB[2][256 * 64];
    const int t = threadIdx.x;
    const int wave = t >> 6, lane = t & 63;
    const int quad = lane >> 4, l16 = lane & 15;
    const int wm = wave >> 2, wn = wave & 3;
    const int m0 = blockIdx.x * 256, n0 = blockIdx.y * 256;
    const int nt = K >> 6;              // K-tiles (even, >= 4)

    f4v acc[8][4] = {};

    stage_half<64, 2>(A, m0, K, 0, 0, smA[0], t);
    stage_half<64, 2>(A, m0, K, 0, 1, smA[0] + 8192, t);
    stage_half<32, 2>(Bt, n0, K, 0, 0, smB[0], t);
    stage_half<32, 2>(Bt, n0, K, 0, 1, smB[0] + 8192, t);
    stage_half<64, 2>(A, m0, K, 64, 0, smA[1], t);
    stage_half<32, 2>(Bt, n0, K, 64, 0, smB[1], t);
    stage_half<32, 2>(Bt, n0, K, 64, 1, smB[1] + 8192, t);
    wait_vmcnt<6>();
    __builtin_amdgcn_s_barrier();

    for (int i = 0; i < nt / 2 - 1; ++i) {
        const int kb = 2 * i * 64;
        half_8ph(A, Bt, m0, n0, K, kb + 64, kb + 128, true,
                 smA[0], smB[0], smA[0], smB[0], smA[1],
                 wm, wn, l16, quad, t, acc);
        half_8ph(A, Bt, m0, n0, K, kb + 128, kb + 192, true,
                 smA[1], smB[1], smA[1], smB[1], smA[0],
                 wm, wn, l16, quad, t, acc);
    }
    half_8ph(A, Bt, m0, n0, K, (nt - 1) * 64, 0, false,
             smA[0], smB[0], smA[0], smB[0], smA[1],
             wm, wn, l16, quad, t, acc);
    __builtin_amdgcn_s_setprio(1);
    comp_full(smA[1], smB[1], wm, wn, l16, quad, acc);
    __builtin_amdgcn_s_setprio(0);

#pragma unroll
    for (int mi = 0; mi < 8; mi++) {
#pragma unroll
        for (int ni = 0; ni < 4; ni++) {
            const int col = n0 + wn * 64 + ni * 16 + l16;
            const int row0 = m0 + wm * 128 + mi * 16 + quad * 4;
            const float bv = bias[col];
#pragma unroll
            for (int r = 0; r < 4; r++) {
                float v = acc[mi][ni][r] + bv;
                if (RELU) v = v > 0.f ? v : 0.f;
                size_t cidx;
                if constexpr (SPLIT3)
                    cidx = (size_t)(col >> 10) * ((size_t)NTOK * 1024)
                         + (size_t)(row0 + r) * 1024 + (col & 1023);
                else
                    cidx = (size_t)(row0 + r) * N + col;
                if constexpr (sizeof(CT) == 2)
                    C[cidx] = f2b(v);
                else
                    C[cidx] = v;
            }
        }
    }
}

// ======== gemm128k: BM=BN=128, 8 waves (2M x 2N x 2K-split), 2 blocks/CU =========
// Each wave accumulates one 32-wide k-half of every 64-k tile (s = wave>>2); the
// two halves are combined through LDS in the epilogue. 64 KB LDS -> 2 blocks/CU,
// so one block's stage/barrier stalls hide under the other's MFMA (m114 mechanism).
// split-K=2 over z: z=0 -> C = acc + bias + res, z=1 -> pbuf = acc.

__device__ __forceinline__ void stage128(const unsigned short* __restrict__ mat,
                                         int base, int K, int k0,
                                         unsigned short* sdst, int t) {
#pragma unroll
    for (int q = 0; q < 2; q++) {
        int rl = t >> 3;                    // 0..63
        int c  = (t & 7) ^ (rl & 7);        // pre-swizzled source column
        gload_lds16(mat + (size_t)(base + q * 64 + rl) * K + k0 + c * 8,
                    sdst + q * 4096 + (size_t)t * 8);
    }
}

__device__ __forceinline__ s8v rdfrag128(const unsigned short* sm, int q, int fi,
                                         int l16, int quad, int sW) {
    int rl = fi * 16 + l16;
    int p = (sW * 4 + quad) ^ (l16 & 7);
    return *(const s8v*)&sm[q * 4096 + rl * 64 + p * 8];
}

__global__ __launch_bounds__(512, 4) void gemm128k(const unsigned short* __restrict__ A,
                                                   const unsigned short* __restrict__ Bt,
                                                   const float* __restrict__ bias,
                                                   const float* __restrict__ res,
                                                   float* __restrict__ C,
                                                   float* __restrict__ pbuf,
                                                   int M, int N, int K, int KS) {
    __shared__ __align__(16) unsigned short smem[4][8192];  // [0,1]=A dbuf, [2,3]=B dbuf
    const int t = threadIdx.x;
    const int wave = t >> 6, lane = t & 63;
    const int quad = lane >> 4, l16 = lane & 15;
    const int sW = wave >> 2, wm = (wave >> 1) & 1, wn = wave & 1;
    const int m0 = blockIdx.x * 128, n0 = blockIdx.y * 128;
    const int z = blockIdx.z;
    const int kbeg = z * KS;
    const int nt = KS >> 6;             // >= 2

    f4v acc[4][4] = {};

    // prologue: tiles 0,1 in flight; wait tile 0 (4 loads/thread/tile)
    stage128(A,  m0, K, kbeg,      smem[0], t);
    stage128(Bt, n0, K, kbeg,      smem[2], t);
    stage128(A,  m0, K, kbeg + 64, smem[1], t);
    stage128(Bt, n0, K, kbeg + 64, smem[3], t);
    wait_vmcnt<4>();
    __builtin_amdgcn_s_barrier();

    for (int it = 0; it < nt; ++it) {
        const int cb = it & 1;
        const unsigned short* sA = smem[cb];
        const unsigned short* sB = smem[2 + cb];
        s8v a[4], b[4];
#pragma unroll
        for (int i = 0; i < 4; i++) a[i] = rdfrag128(sA, wm, i, l16, quad, sW);
#pragma unroll
        for (int i = 0; i < 4; i++) b[i] = rdfrag128(sB, wn, i, l16, quad, sW);
        asm volatile("s_waitcnt lgkmcnt(0)" ::: "memory");
        __builtin_amdgcn_s_setprio(1);
#pragma unroll
        for (int mi = 0; mi < 4; mi++)
#pragma unroll
            for (int ni = 0; ni < 4; ni++)
                acc[mi][ni] = mfma_bf16(a[mi], b[ni], acc[mi][ni]);
        __builtin_amdgcn_s_setprio(0);
        __builtin_amdgcn_s_barrier();       // all waves done reading buf cb
        if (it + 2 < nt) {
            stage128(A,  m0, K, kbeg + (it + 2) * 64, smem[cb], t);
            stage128(Bt, n0, K, kbeg + (it + 2) * 64, smem[2 + cb], t);
            wait_vmcnt<4>();                // tile it+1 landed; it+2 in flight
        } else if (it + 1 < nt) {
            wait_vmcnt<0>();                // last tile landed
        }
        __builtin_amdgcn_s_barrier();       // publish tile it+1
    }

    // combine the two K-split halves: sW=1 exports acc via LDS; sW=0 adds + writes
    float* xch = (float*)&smem[0][0];
    float* myx = xch + (wm * 2 + wn) * 4096;    // 16 KB per pair, 64 KB total
    if (sW == 1) {
#pragma unroll
        for (int mi = 0; mi < 4; mi++)
#pragma unroll
            for (int ni = 0; ni < 4; ni++)
                *(f4v*)&myx[(mi * 4 + ni) * 256 + lane * 4] = acc[mi][ni];
    }
    __builtin_amdgcn_s_barrier();
    if (sW == 0) {
#pragma unroll
        for (int mi = 0; mi < 4; mi++)
#pragma unroll
            for (int ni = 0; ni < 4; ni++)
                acc[mi][ni] += *(const f4v*)&myx[(mi * 4 + ni) * 256 + lane * 4];
#pragma unroll
        for (int mi = 0; mi < 4; mi++)
#pragma unroll
            for (int ni = 0; ni < 4; ni++) {
                const int col = n0 + wn * 64 + ni * 16 + l16;
                const int row0 = m0 + wm * 64 + mi * 16 + quad * 4;
                if (z == 0) {
                    const float bv = bias[col];
#pragma unroll
                    for (int r = 0; r < 4; r++) {
                        size_t ix = (size_t)(row0 + r) * N + col;
                        C[ix] = acc[mi][ni][r] + bv + res[ix];
                    }
                } else {
#pragma unroll
                    for (int r = 0; r < 4; r++)
                        pbuf[(size_t)(row0 + r) * N + col] = acc[mi][ni][r];
                }
            }
    }
}

// ============ flash attention v3: compacted keys, 128 q/block, dbuf, exp2 softmax ========
#define EXPC 0.18033688f   // 0.125 * log2(e)
__device__ __forceinline__ void attn_tile(const unsigned short* __restrict__ smKb,
                                          const unsigned short* __restrict__ smVb,
                                          const float* __restrict__ smM, int k0,
                                          unsigned short* __restrict__ smPw,
                                          s8v qf0, s8v qf1, int quad, int l16,
                                          float& l_s, f4v* oacc) {
    const int l7 = l16 & 7;
    f4v s[4];
#pragma unroll
    for (int kt4 = 0; kt4 < 4; kt4++) {
        int r = kt4 * 16 + l16;
        s8v kf0 = *(const s8v*)&smKb[r * 64 + ((quad ^ l7) * 8)];
        s8v kf1 = *(const s8v*)&smKb[r * 64 + (((quad + 4) ^ l7) * 8)];
        f4v z = {};
        z = mfma_bf16(kf0, qf0, z);
        z = mfma_bf16(kf1, qf1, z);
        s[kt4] = z;
    }
#pragma unroll
    for (int kt4 = 0; kt4 < 4; kt4++) {
        float4 mf = *(const float4*)&smM[k0 + kt4 * 16 + quad * 4];
        s[kt4][0] = s[kt4][0] * EXPC + mf.x;
        s[kt4][1] = s[kt4][1] * EXPC + mf.y;
        s[kt4][2] = s[kt4][2] * EXPC + mf.z;
        s[kt4][3] = s[kt4][3] * EXPC + mf.w;
    }
#pragma unroll
    for (int kt4 = 0; kt4 < 4; kt4++)
#pragma unroll
        for (int r = 0; r < 4; r++) {
            float p = __builtin_amdgcn_exp2f(s[kt4][r]);
            s[kt4][r] = p;
            l_s += p;
        }
#pragma unroll
    for (int kt4 = 0; kt4 < 4; kt4++) {
        ushort2 p01 = cvt_pk(s[kt4][0], s[kt4][1]);
        ushort2 p23 = cvt_pk(s[kt4][2], s[kt4][3]);
        ushort4 pk;
        pk.x = p01.x; pk.y = p01.y; pk.z = p23.x; pk.w = p23.y;
        int c = kt4 * 2 + (quad >> 1);
        *(ushort4*)&smPw[l16 * 64 + ((c ^ l7) * 8 + (quad & 1) * 4)] = pk;
    }
    s8v pf0 = *(const s8v*)&smPw[l16 * 64 + ((quad ^ l7) * 8)];
    s8v pf1 = *(const s8v*)&smPw[l16 * 64 + (((quad + 4) ^ l7) * 8)];
#pragma unroll
    for (int nt = 0; nt < 4; nt++) {
        int r = nt * 16 + l16;
        s8v v0 = *(const s8v*)&smVb[r * 64 + ((quad ^ l7) * 8)];
        s8v v1 = *(const s8v*)&smVb[r * 64 + (((quad + 4) ^ l7) * 8)];
        oacc[nt] = mfma_bf16(pf0, v0, oacc[nt]);
        oacc[nt] = mfma_bf16(pf1, v1, oacc[nt]);
    }
}

__global__ __launch_bounds__(512) void attn_kernel(const unsigned short* __restrict__ Qb,
                                                   const unsigned short* __restrict__ Kc,
                                                   const unsigned short* __restrict__ Vc,
                                                   const float* __restrict__ maskc2,
                                                   const int* __restrict__ ntiles,
                                                   unsigned short* __restrict__ out) {
    __shared__ __align__(16) unsigned short smK[2][4096];   // 64 keys x 64 d, swizzled
    __shared__ __align__(16) unsigned short smV[2][4096];   // 64 d x 64 keys, swizzled
    __shared__ __align__(16) unsigned short smP[8][1024];   // per-wave P, swizzled stride 64
    __shared__ __align__(16) float smM[SEQ];                // compacted mask row (pads=-1e9)

    const int t = threadIdx.x;
    const int wave = t >> 6, lane = t & 63;
    const int quad = lane >> 4, l16 = lane & 15;
    const int qt = blockIdx.x, h = blockIdx.y, b = blockIdx.z;
    const int q0 = qt * 128 + wave * 16;
    const int nt = ntiles[b];
    const unsigned short* Kbh = Kc + ((size_t)(b * NHEAD + h)) * 32 * 4096;
    const unsigned short* Vbh = Vc + ((size_t)(b * NHEAD + h)) * 32 * 4096;
    unsigned short* smPw = &smP[wave][0];

    const unsigned short* Qp = Qb + ((size_t)b * SEQ + q0 + l16) * 1024 + h * HDIM + quad * 8;
    s8v qf0 = *(const s8v*)(Qp);
    s8v qf1 = *(const s8v*)(Qp + 32);

    gload_lds16(maskc2 + (size_t)b * SEQ + t * 4, (float*)smM + t * 4);
    gload_lds16(Kbh + t * 8,        smK[0] + t * 8);
    gload_lds16(Vbh + t * 8,        smV[0] + t * 8);
    gload_lds16(Kbh + 4096 + t * 8, smK[1] + t * 8);
    gload_lds16(Vbh + 4096 + t * 8, smV[1] + t * 8);
    wait_vmcnt<2>();
    __builtin_amdgcn_s_barrier();

    float l_s = 0.f;
    f4v oacc[4] = {};

    for (int it = 0; it < nt; ++it) {
        const int cb = it & 1;
        __builtin_amdgcn_s_setprio(1);
        attn_tile(smK[cb], smV[cb], smM, it * 64, smPw, qf0, qf1, quad, l16, l_s, oacc);
        __builtin_amdgcn_s_setprio(0);
        if (it + 2 < nt) {
            asm volatile("s_waitcnt lgkmcnt(0)" ::: "memory");
            __builtin_amdgcn_s_barrier();
            gload_lds16(Kbh + (size_t)(it + 2) * 4096 + t * 8, smK[cb] + t * 8);
            gload_lds16(Vbh + (size_t)(it + 2) * 4096 + t * 8, smV[cb] + t * 8);
            wait_vmcnt<2>();
            __builtin_amdgcn_s_barrier();
        } else if (it + 1 < nt) {
            asm volatile("s_waitcnt lgkmcnt(0)" ::: "memory");
            __builtin_amdgcn_s_barrier();
            wait_vmcnt<0>();
            __builtin_amdgcn_s_barrier();
        }
    }

    l_s += __shfl_xor(l_s, 16);
    l_s += __shfl_xor(l_s, 32);
    float lrr[4];
    for (int r = 0; r < 4; r++) lrr[r] = __shfl(l_s, quad * 4 + r);
    for (int nt2 = 0; nt2 < 4; nt2++)
        for (int r = 0; r < 4; r++) {
            int row = q0 + quad * 4 + r;
            int col = h * HDIM + nt2 * 16 + l16;
            out[((size_t)b * SEQ + row) * DMODEL + col] = f2b(oacc[nt2][r] / lrr[r]);
        }
}

extern "C" void kernel_launch(void* const* d_in, const int* in_sizes, int n_in,
                              void* d_out, int out_size, void* d_ws, size_t ws_size,
                              hipStream_t stream) {
    const float* x   = (const float*)d_in[0];
    const int*   msk = (const int*)d_in[1];
    const float* Wq  = (const float*)d_in[2];
    const float* bq  = (const float*)d_in[3];
    const float* Wk  = (const float*)d_in[4];
    const float* bk  = (const float*)d_in[5];
    const float* Wv  = (const float*)d_in[6];
    const float* bv  = (const float*)d_in[7];
    const float* Wo  = (const float*)d_in[8];
    const float* bo  = (const float*)d_in[9];
    const float* W1  = (const float*)d_in[10];
    const float* b1  = (const float*)d_in[11];
    const float* W2  = (const float*)d_in[12];
    const float* b2  = (const float*)d_in[13];
    const float* a1  = (const float*)d_in[14];
    const float* be1 = (const float*)d_in[15];
    const float* a2  = (const float*)d_in[16];
    const float* be2 = (const float*)d_in[17];
    float* outf = (float*)d_out;   // 4096x1024 fp32 = 16 MB

    // ---- arena (R5 layout: ws + d_out reuse) ----
    char* ws = (char*)d_ws;
    const size_t MB = 1024 * 1024;
    unsigned short* W2_t   = (unsigned short*)(ws);
    unsigned short* W1_t   = (unsigned short*)(ws + 8 * MB);
    float*          Pbuf   = (float*)(ws + 8 * MB);
    unsigned short* Wqkv_t = (unsigned short*)(ws + 16 * MB);
    float*          bqkv   = (float*)(ws + 22 * MB);
    unsigned short* Kc     = (unsigned short*)(ws + 16 * MB);
    unsigned short* n2     = (unsigned short*)(ws + 16 * MB);
    unsigned short* Wo_t   = (unsigned short*)(ws + 24 * MB);
    unsigned short* Qb     = (unsigned short*)(ws + 26 * MB);
    unsigned short* Kb     = (unsigned short*)(ws + 34 * MB);
    unsigned short* Vb     = (unsigned short*)(ws + 42 * MB);
    float*          Pbuf2  = (float*)(ws + 34 * MB);   // 16 MB over dead Kb/Vb (phase 5)
    unsigned short* ff1    = (unsigned short*)(ws + 26 * MB);
    unsigned short* attnO  = (unsigned short*)(ws + 50 * MB);
    unsigned short* n1     = (unsigned short*)d_out;                 // [0,8) MB, ph1-3
    unsigned short* Vc     = (unsigned short*)d_out;                 // [0,8) MB, ph3.5-4
    float*          hbuf   = (float*)d_out;                          // 16 MB, ph5-9
    float*          maskc2 = (float*)((char*)d_out + 8 * MB);            // 16 KB
    int*            idxc   = (int*)((char*)d_out + 8 * MB + 16 * 1024);  // 16 KB
    int*            ntl    = (int*)((char*)d_out + 8 * MB + 32 * 1024);  // 8 B

    // phase 0: mask compaction scan
    mask_scan<<<dim3(BATCH), 256, 0, stream>>>(msk, idxc, maskc2, ntl);
    // phase 1: weight transposes + bias concat + LN1
    prep_weights<<<dim3(16, 16, 22), 256, 0, stream>>>(
        Wq, Wk, Wv, Wo, W1, W2, bq, bk, bv, x, a1, be1,
        Wqkv_t, Wo_t, W1_t, W2_t, bqkv, n1);

    // phase 3: [Q|K|V] = n1 @ Wqkv + bias (256x256 8-phase, SPLIT3)
    gemm256<false, unsigned short, true><<<dim3(16, 12), 512, 0, stream>>>(
        n1, Wqkv_t, bqkv, Qb, NTOK, 3072, 1024);
    // phase 3.5: pack compacted K/V (Kb/Vb die here)
    pack_kv<<<dim3(32, 16, 2), 256, 0, stream>>>(Kb, Vb, idxc, ntl, Kc, Vc);
    // phase 4: attention over compacted keys
    attn_kernel<<<dim3(16, 16, 2), 512, 0, stream>>>(Qb, Kc, Vc, maskc2, ntl, attnO);
    // phase 5: h = x + attnO @ Wo^T + bo (gemm128k split-K=2: z=0 -> hbuf, z=1 -> Pbuf2)
    gemm128k<<<dim3(32, 8, 2), 512, 0, stream>>>(
        attnO, Wo_t, bo, x, hbuf, Pbuf2, NTOK, 1024, 1024, 512);
    // phase 6: h += Pbuf2 (write back) ; n2 = LN2(h)  (fused)
    ln_add<<<NTOK, 256, 0, stream>>>(hbuf, Pbuf2, a2, be2, n2);
    // phase 7: ff1 = relu(n2 @ W1 + b1) (8-phase BN=256)
    gemm256<true, unsigned short, false><<<dim3(16, 16), 512, 0, stream>>>(
        n2, W1_t, b1, ff1, NTOK, DFF, 1024);
    // phase 8: ff2 (gemm128k split-K=2: z=0 -> out = h + b2 + acc, z=1 -> Pbuf)
    gemm128k<<<dim3(32, 8, 2), 512, 0, stream>>>(
        ff1, W2_t, b2, hbuf, outf, Pbuf, NTOK, 1024, 4096, 2048);
    // phase 9: out += Pbuf
    add_pbuf<<<dim3(2048), 256, 0, stream>>>(outf, Pbuf);
}